// Round 2
// baseline (261.546 us; speedup 1.0000x reference)
//
#include <hip/hip_runtime.h>
#include <hip/hip_bf16.h>

#define NN 8192
#define HH 256
#define EE (NN*32)
#define ALPHAC 0.2f
#define CHUNK 64
#define NCHUNK (NN/CHUNK)   // 128

// workspace layout (float offsets)
#define OFF_WH     0
#define OFF_S      (OFF_WH + NN*HH)
#define OFF_D      (OFF_S + NN)
#define OFF_SORTD  (OFF_D + NN)
#define OFF_PERM   (OFF_SORTD + NN)   /* ints */
#define OFF_EA     (OFF_PERM + NN)
#define OFF_E1     (OFF_EA + NN)
#define OFF_APREF  (OFF_E1 + NN)
#define OFF_BPREF  (OFF_APREF + NN)
#define OFF_APART  (OFF_BPREF + NN)
#define OFF_BPART  (OFF_APART + NN*HH)
#define OFF_CTA    (OFF_BPART + NN*HH)
#define OFF_CTB    (OFF_CTA + NCHUNK*HH)
#define OFF_CPA    (OFF_CTB + NCHUNK*HH)
#define OFF_CPB    (OFF_CPA + (NCHUNK+1)*HH)
#define OFF_DEG    (OFF_CPB + (NCHUNK+1)*HH)
#define OFF_DINV   (OFF_DEG + NN)
#define OFF_WNODE  (OFF_DINV + NN)
#define OFF_V      (OFF_WNODE + NN)

__global__ void k_init(float* ws) {
    int i = blockIdx.x*256 + threadIdx.x;
    if (i < NN) ws[OFF_DEG + i] = 1.0f;          // self-loop contributes 1 to degree
    if (i < HH) ws[OFF_V + i] = 0.0f;
}

// Wh = features[NN,HH] @ W_att[HH,HH]  (f32, 64x64 tile, BK=32)
__global__ __launch_bounds__(256) void k_gemm_wh(const float* __restrict__ A,
                                                 const float* __restrict__ B,
                                                 float* __restrict__ C) {
    __shared__ float As[32][68];   // As[k][row]
    __shared__ float Bs[32][68];   // Bs[k][col]
    int tid = threadIdx.x;
    int row0 = blockIdx.x * 64, col0 = blockIdx.y * 64;
    int tx = tid & 15, ty = tid >> 4;
    float acc[4][4] = {};
    int a_r = tid >> 2;
    int a_k = (tid & 3) * 8;
    int b_k = tid >> 3;
    int b_c = (tid & 7) * 8;
    const float* Aptr = A + (size_t)(row0 + a_r)*HH + a_k;
    const float* Bptr = B + (size_t)b_k*HH + col0 + b_c;
    for (int k0 = 0; k0 < HH; k0 += 32) {
        float4 av0 = *(const float4*)(Aptr + k0);
        float4 av1 = *(const float4*)(Aptr + k0 + 4);
        float4 bv0 = *(const float4*)(Bptr + (size_t)k0*HH);
        float4 bv1 = *(const float4*)(Bptr + (size_t)k0*HH + 4);
        __syncthreads();
        As[a_k+0][a_r] = av0.x; As[a_k+1][a_r] = av0.y;
        As[a_k+2][a_r] = av0.z; As[a_k+3][a_r] = av0.w;
        As[a_k+4][a_r] = av1.x; As[a_k+5][a_r] = av1.y;
        As[a_k+6][a_r] = av1.z; As[a_k+7][a_r] = av1.w;
        *(float4*)&Bs[b_k][b_c]   = bv0;
        *(float4*)&Bs[b_k][b_c+4] = bv1;
        __syncthreads();
        #pragma unroll
        for (int kk = 0; kk < 32; ++kk) {
            float4 ar = *(const float4*)&As[kk][ty*4];
            float4 br = *(const float4*)&Bs[kk][tx*4];
            float a0[4] = {ar.x, ar.y, ar.z, ar.w};
            float b0[4] = {br.x, br.y, br.z, br.w};
            #pragma unroll
            for (int r = 0; r < 4; ++r)
                #pragma unroll
                for (int c = 0; c < 4; ++c)
                    acc[r][c] += a0[r]*b0[c];
        }
    }
    #pragma unroll
    for (int r = 0; r < 4; ++r) {
        float4 o = make_float4(acc[r][0], acc[r][1], acc[r][2], acc[r][3]);
        *(float4*)(C + (size_t)(row0 + ty*4 + r)*HH + col0 + tx*4) = o;
    }
}

// s_i = Wh[i]·a_src, d_i = Wh[i]·a_dst  — one wave per row
__global__ void k_sd(const float* __restrict__ Wh, const float* __restrict__ a_src,
                     const float* __restrict__ a_dst, float* ws) {
    int wave = threadIdx.x >> 6, lane = threadIdx.x & 63;
    int row = blockIdx.x*4 + wave;
    float4 wh = *(const float4*)(Wh + (size_t)row*HH + lane*4);
    float4 as = *(const float4*)(a_src + lane*4);
    float4 ad = *(const float4*)(a_dst + lane*4);
    float ss = wh.x*as.x + wh.y*as.y + wh.z*as.z + wh.w*as.w;
    float dd = wh.x*ad.x + wh.y*ad.y + wh.z*ad.z + wh.w*ad.w;
    #pragma unroll
    for (int off = 32; off; off >>= 1) {
        ss += __shfl_xor(ss, off);
        dd += __shfl_xor(dd, off);
    }
    if (lane == 0) { ws[OFF_S+row] = ss; ws[OFF_D+row] = dd; }
}

// rank each d_j by counting. 256 blocks x 256 thr; 2 elements per thread;
// 16 subs x 512-wide q ranges; float4 LDS reads with rotated start so banks
// are (4*(it+sub))%32 -> exactly 2-way aliasing (free per m136).
__global__ __launch_bounds__(256) void k_rank(float* ws) {
    __shared__ float ld[NN];    // 32 KB
    const float* d = ws + OFF_D;
    int tid = threadIdx.x;
    for (int m = tid; m < NN/4; m += 256)
        *(float4*)&ld[m*4] = *(const float4*)&d[m*4];
    __syncthreads();
    int jg  = tid >> 4;               // 0..15
    int sub = tid & 15;               // 0..15
    int j0 = blockIdx.x*32 + jg;
    int j1 = j0 + 16;
    float dj0 = ld[j0], dj1 = ld[j1];
    int c0 = 0, c1 = 0;
    int base = sub * 512;
    #pragma unroll 4
    for (int it = 0; it < 128; ++it) {
        int idx = base + (((it + sub) & 127) << 2);
        float4 v = *(const float4*)&ld[idx];
        c0 += (v.x < dj0) || (v.x == dj0 && idx+0 < j0);
        c0 += (v.y < dj0) || (v.y == dj0 && idx+1 < j0);
        c0 += (v.z < dj0) || (v.z == dj0 && idx+2 < j0);
        c0 += (v.w < dj0) || (v.w == dj0 && idx+3 < j0);
        c1 += (v.x < dj1) || (v.x == dj1 && idx+0 < j1);
        c1 += (v.y < dj1) || (v.y == dj1 && idx+1 < j1);
        c1 += (v.z < dj1) || (v.z == dj1 && idx+2 < j1);
        c1 += (v.w < dj1) || (v.w == dj1 && idx+3 < j1);
    }
    #pragma unroll
    for (int off = 1; off < 16; off <<= 1) {
        c0 += __shfl_xor(c0, off);
        c1 += __shfl_xor(c1, off);
    }
    if (sub == 0) {
        ws[OFF_SORTD + c0] = dj0;
        ((int*)ws)[OFF_PERM + c0] = j0;
        ws[OFF_EA + c0] = expf(ALPHAC * dj0);
        ws[OFF_E1 + c0] = expf(dj0);
        ws[OFF_SORTD + c1] = dj1;
        ((int*)ws)[OFF_PERM + c1] = j1;
        ws[OFF_EA + c1] = expf(ALPHAC * dj1);
        ws[OFF_E1 + c1] = expf(dj1);
    }
}

// inclusive scalar prefix sums of ea, e1 over sorted order (1 block)
__global__ void k_scan_scalar(float* ws) {
    __shared__ float sa[256], sb[256];
    int t = threadIdx.x;
    const float* ea = ws + OFF_EA;
    const float* e1 = ws + OFF_E1;
    int base = t * 32;
    float ta = 0.f, tb = 0.f;
    for (int q = 0; q < 32; ++q) { ta += ea[base+q]; tb += e1[base+q]; }
    sa[t] = ta; sb[t] = tb;
    __syncthreads();
    for (int off = 1; off < 256; off <<= 1) {
        float xa = (t >= off) ? sa[t-off] : 0.f;
        float xb = (t >= off) ? sb[t-off] : 0.f;
        __syncthreads();
        sa[t] += xa; sb[t] += xb;
        __syncthreads();
    }
    float ra = sa[t] - ta, rb = sb[t] - tb;
    for (int q = 0; q < 32; ++q) {
        ra += ea[base+q]; ws[OFF_APREF+base+q] = ra;
        rb += e1[base+q]; ws[OFF_BPREF+base+q] = rb;
    }
}

// per-chunk inclusive vector prefixes of exp(alpha d)*Wh and exp(d)*Wh (sorted order)
__global__ __launch_bounds__(256) void k_vecpref(float* ws) {
    __shared__ int   sp[CHUNK];
    __shared__ float sea[CHUNK], se1[CHUNK];
    int c = blockIdx.x, h = threadIdx.x;
    int k0 = c * CHUNK;
    if (h < CHUNK) {
        sp[h]  = ((int*)ws)[OFF_PERM + k0 + h];
        sea[h] = ws[OFF_EA + k0 + h];
        se1[h] = ws[OFF_E1 + k0 + h];
    }
    __syncthreads();
    const float* Wh = ws + OFF_WH;
    float acca = 0.f, accb = 0.f;
    for (int kk = 0; kk < CHUNK; ++kk) {
        float w = Wh[(size_t)sp[kk]*HH + h];
        acca += sea[kk]*w; accb += se1[kk]*w;
        ws[OFF_APART + (size_t)(k0+kk)*HH + h] = acca;
        ws[OFF_BPART + (size_t)(k0+kk)*HH + h] = accb;
    }
    ws[OFF_CTA + (size_t)c*HH + h] = acca;
    ws[OFF_CTB + (size_t)c*HH + h] = accb;
}

// exclusive scan of chunk totals (entry NCHUNK = grand total)
// 32 blocks x 256 thr: 8 h-columns per block, 32 lanes per column, 4 chunks/lane
__global__ __launch_bounds__(256) void k_chunkscan(float* ws) {
    int tid = threadIdx.x;
    int h = blockIdx.x*8 + (tid >> 5);
    int t = tid & 31;
    float la[4], lb[4];
    float ta = 0.f, tb = 0.f;
    #pragma unroll
    for (int m = 0; m < 4; ++m) {
        int c = t*4 + m;
        la[m] = ws[OFF_CTA + (size_t)c*HH + h];
        lb[m] = ws[OFF_CTB + (size_t)c*HH + h];
        ta += la[m]; tb += lb[m];
    }
    float ia = ta, ib = tb;
    #pragma unroll
    for (int off = 1; off < 32; off <<= 1) {
        float xa = __shfl_up(ia, off, 32);
        float xb = __shfl_up(ib, off, 32);
        if (t >= off) { ia += xa; ib += xb; }
    }
    float ba = ia - ta, bb = ib - tb;   // exclusive base
    #pragma unroll
    for (int m = 0; m < 4; ++m) {
        int c = t*4 + m;
        ws[OFF_CPA + (size_t)c*HH + h] = ba;
        ws[OFF_CPB + (size_t)c*HH + h] = bb;
        ba += la[m]; bb += lb[m];
    }
    if (t == 31) {
        ws[OFF_CPA + (size_t)NCHUNK*HH + h] = ba;
        ws[OFF_CPB + (size_t)NCHUNK*HH + h] = bb;
    }
}

__global__ void k_deg(const int* __restrict__ ei, float* ws) {
    int e = blockIdx.x*256 + threadIdx.x;
    if (e < EE) atomicAdd(ws + OFF_DEG + ei[e], 1.0f);
}

__global__ void k_dinv(float* ws) {
    int i = blockIdx.x*256 + threadIdx.x;
    if (i < NN) {
        float dv = rsqrtf(ws[OFF_DEG + i]);
        ws[OFF_DINV + i] = dv;
        ws[OFF_WNODE + i] = dv*dv;     // self-loop term
    }
}

__global__ void k_wnode(const int* __restrict__ ei, float* ws) {
    int e = blockIdx.x*256 + threadIdx.x;
    if (e < EE) {
        int r = ei[e], c = ei[EE + e];
        atomicAdd(ws + OFF_WNODE + c, ws[OFF_DINV + r] * ws[OFF_DINV + c]);
    }
}

__device__ __forceinline__ float elu1(float x) {
    return x > 0.f ? x : (expf(x) - 1.f);
}

// per-row attention via prefix lookup; accumulate v = sum_i wnode[i]*h1[i]
// binary searches for the wave's 8 rows run in parallel on lanes 0..7.
__global__ __launch_bounds__(256) void k_rows(float* ws) {
    __shared__ float sd[NN];       // 32 KB sorted d
    __shared__ float red[4][256];
    int tid = threadIdx.x;
    for (int m = tid; m < NN/4; m += 256)
        *(float4*)&sd[m*4] = *(const float4*)(ws + OFF_SORTD + m*4);
    __syncthreads();
    int wave = tid >> 6, lane = tid & 63;
    int gw = blockIdx.x*4 + wave;            // 0..1023
    const float* apart = ws + OFF_APART;
    const float* bpart = ws + OFF_BPART;
    const float* cpa = ws + OFF_CPA;
    const float* cpb = ws + OFF_CPB;
    float btot = ws[OFF_BPREF + NN - 1];
    float4 BT = *(const float4*)(cpb + (size_t)NCHUNK*HH + lane*4);

    // parallel binary search: lane l searches for row gw*8 + (l&7)
    int myr = lane & 7;
    float si_m = ws[OFF_S + gw*8 + myr];
    float tt = -si_m;
    int lo = 0, hi = NN;
    while (lo < hi) {
        int mid = (lo + hi) >> 1;
        if (sd[mid] <= tt) lo = mid + 1; else hi = mid;
    }

    float accx = 0.f, accy = 0.f, accz = 0.f, accw = 0.f;
    #pragma unroll
    for (int r = 0; r < 8; ++r) {
        int i = gw*8 + r;
        int k = __shfl(lo, r);
        float si = __shfl(si_m, r);
        float eas = expf(ALPHAC * si), es = expf(si);
        float av = 0.f, bv = 0.f;
        float Ax=0.f, Ay=0.f, Az=0.f, Aw=0.f, Bx=0.f, By=0.f, Bz=0.f, Bw=0.f;
        if (k > 0) {
            int km = k - 1, cc = km >> 6;
            av = ws[OFF_APREF + km]; bv = ws[OFF_BPREF + km];
            float4 pa = *(const float4*)(apart + (size_t)km*HH + lane*4);
            float4 ca = *(const float4*)(cpa + (size_t)cc*HH + lane*4);
            float4 pb = *(const float4*)(bpart + (size_t)km*HH + lane*4);
            float4 cb = *(const float4*)(cpb + (size_t)cc*HH + lane*4);
            Ax = pa.x + ca.x; Ay = pa.y + ca.y; Az = pa.z + ca.z; Aw = pa.w + ca.w;
            Bx = pb.x + cb.x; By = pb.y + cb.y; Bz = pb.z + cb.z; Bw = pb.w + cb.w;
        }
        float Z = eas*av + es*(btot - bv);
        float invZ = 1.f / Z;
        float w = ws[OFF_WNODE + i];
        accx += w * elu1((eas*Ax + es*(BT.x - Bx)) * invZ);
        accy += w * elu1((eas*Ay + es*(BT.y - By)) * invZ);
        accz += w * elu1((eas*Az + es*(BT.z - Bz)) * invZ);
        accw += w * elu1((eas*Aw + es*(BT.w - Bw)) * invZ);
    }
    red[wave][lane*4+0] = accx;
    red[wave][lane*4+1] = accy;
    red[wave][lane*4+2] = accz;
    red[wave][lane*4+3] = accw;
    __syncthreads();
    float sum = red[0][tid] + red[1][tid] + red[2][tid] + red[3][tid];
    atomicAdd(ws + OFF_V + tid, sum);
}

// head: (v @ gcn_w)/N + gcn_b -> @ out_w + out_b -> softmax(2)
__global__ void k_final(const float* __restrict__ gcn_w, const float* __restrict__ gcn_b,
                        const float* __restrict__ out_w, const float* __restrict__ out_b,
                        float* ws, float* out) {
    __shared__ float vl[HH];
    __shared__ float r0s[256], r1s[256];
    int t = threadIdx.x;
    vl[t] = ws[OFF_V + t];
    __syncthreads();
    float acc = 0.f;
    for (int h = 0; h < HH; ++h) acc += vl[h] * gcn_w[(size_t)h*HH + t];
    float meanv = acc * (1.0f/(float)NN) + gcn_b[t];
    r0s[t] = meanv * out_w[t*2+0];
    r1s[t] = meanv * out_w[t*2+1];
    __syncthreads();
    for (int off = 128; off; off >>= 1) {
        if (t < off) { r0s[t] += r0s[t+off]; r1s[t] += r1s[t+off]; }
        __syncthreads();
    }
    if (t == 0) {
        float res0 = r0s[0] + out_b[0], res1 = r1s[0] + out_b[1];
        float m = fmaxf(res0, res1);
        float e0 = expf(res0 - m), e1v = expf(res1 - m);
        float inv = 1.f / (e0 + e1v);
        out[0] = e0 * inv;
        out[1] = e1v * inv;
    }
}

extern "C" void kernel_launch(void* const* d_in, const int* in_sizes, int n_in,
                              void* d_out, int out_size, void* d_ws, size_t ws_size,
                              hipStream_t stream) {
    const float* features = (const float*)d_in[0];
    const int*   eidx     = (const int*)d_in[1];
    const float* W_att    = (const float*)d_in[2];
    const float* a_src    = (const float*)d_in[3];
    const float* a_dst    = (const float*)d_in[4];
    const float* gcn_w    = (const float*)d_in[5];
    const float* gcn_b    = (const float*)d_in[6];
    const float* out_w    = (const float*)d_in[7];
    const float* out_b    = (const float*)d_in[8];
    float* ws  = (float*)d_ws;
    float* out = (float*)d_out;

    k_init<<<NN/256, 256, 0, stream>>>(ws);
    k_gemm_wh<<<dim3(NN/64, HH/64), 256, 0, stream>>>(features, W_att, ws + OFF_WH);
    k_sd<<<NN/4, 256, 0, stream>>>(ws + OFF_WH, a_src, a_dst, ws);
    k_rank<<<NN/32, 256, 0, stream>>>(ws);
    k_scan_scalar<<<1, 256, 0, stream>>>(ws);
    k_vecpref<<<NCHUNK, 256, 0, stream>>>(ws);
    k_chunkscan<<<HH/8, 256, 0, stream>>>(ws);
    k_deg<<<EE/256, 256, 0, stream>>>(eidx, ws);
    k_dinv<<<NN/256, 256, 0, stream>>>(ws);
    k_wnode<<<EE/256, 256, 0, stream>>>(eidx, ws);
    k_rows<<<256, 256, 0, stream>>>(ws);
    k_final<<<1, 256, 0, stream>>>(gcn_w, gcn_b, out_w, out_b, ws, out);
}

// Round 3
// 185.540 us; speedup vs baseline: 1.4097x; 1.4097x over previous
//
#include <hip/hip_runtime.h>
#include <hip/hip_bf16.h>

#define NN 8192
#define HH 256
#define EE (NN*32)
#define ALPHAC 0.2f
#define CHUNK 32
#define NCHUNK (NN/CHUNK)   // 256

// workspace layout (float offsets)
#define OFF_WH     0
#define OFF_S      (OFF_WH + NN*HH)
#define OFF_D      (OFF_S + NN)
#define OFF_SORTD  (OFF_D + NN)
#define OFF_PERM   (OFF_SORTD + NN)   /* ints */
#define OFF_EA     (OFF_PERM + NN)
#define OFF_E1     (OFF_EA + NN)
#define OFF_APREF  (OFF_E1 + NN)
#define OFF_BPREF  (OFF_APREF + NN)
#define OFF_APART  (OFF_BPREF + NN)
#define OFF_BPART  (OFF_APART + NN*HH)
#define OFF_CPA    (OFF_BPART + NN*HH)          /* (NCHUNK+1)*HH */
#define OFF_CPB    (OFF_CPA + (NCHUNK+1)*HH)
#define OFF_DEG    (OFF_CPB + (NCHUNK+1)*HH)
#define OFF_V      (OFF_DEG + NN)               /* adjacent to DEG: one memset */
#define OFF_DINV   (OFF_V + HH)
#define OFF_WNODE  (OFF_DINV + NN)
#define OFF_KEYS   (OFF_WNODE + NN)             /* NN u64 = 2*NN floats */
// total = OFF_KEYS + 2*NN = 6,529,792 floats ~ 24.9 MiB

// Wh = features[NN,HH] @ W_att[HH,HH]  (f32, 64x64 tile, BK=32)
__global__ __launch_bounds__(256) void k_gemm_wh(const float* __restrict__ A,
                                                 const float* __restrict__ B,
                                                 float* __restrict__ C) {
    __shared__ float As[32][68];   // As[k][row]
    __shared__ float Bs[32][68];   // Bs[k][col]
    int tid = threadIdx.x;
    int row0 = blockIdx.x * 64, col0 = blockIdx.y * 64;
    int tx = tid & 15, ty = tid >> 4;
    float acc[4][4] = {};
    int a_r = tid >> 2;
    int a_k = (tid & 3) * 8;
    int b_k = tid >> 3;
    int b_c = (tid & 7) * 8;
    const float* Aptr = A + (size_t)(row0 + a_r)*HH + a_k;
    const float* Bptr = B + (size_t)b_k*HH + col0 + b_c;
    for (int k0 = 0; k0 < HH; k0 += 32) {
        float4 av0 = *(const float4*)(Aptr + k0);
        float4 av1 = *(const float4*)(Aptr + k0 + 4);
        float4 bv0 = *(const float4*)(Bptr + (size_t)k0*HH);
        float4 bv1 = *(const float4*)(Bptr + (size_t)k0*HH + 4);
        __syncthreads();
        As[a_k+0][a_r] = av0.x; As[a_k+1][a_r] = av0.y;
        As[a_k+2][a_r] = av0.z; As[a_k+3][a_r] = av0.w;
        As[a_k+4][a_r] = av1.x; As[a_k+5][a_r] = av1.y;
        As[a_k+6][a_r] = av1.z; As[a_k+7][a_r] = av1.w;
        *(float4*)&Bs[b_k][b_c]   = bv0;
        *(float4*)&Bs[b_k][b_c+4] = bv1;
        __syncthreads();
        #pragma unroll
        for (int kk = 0; kk < 32; ++kk) {
            float4 ar = *(const float4*)&As[kk][ty*4];
            float4 br = *(const float4*)&Bs[kk][tx*4];
            float a0[4] = {ar.x, ar.y, ar.z, ar.w};
            float b0[4] = {br.x, br.y, br.z, br.w};
            #pragma unroll
            for (int r = 0; r < 4; ++r)
                #pragma unroll
                for (int c = 0; c < 4; ++c)
                    acc[r][c] += a0[r]*b0[c];
        }
    }
    #pragma unroll
    for (int r = 0; r < 4; ++r) {
        float4 o = make_float4(acc[r][0], acc[r][1], acc[r][2], acc[r][3]);
        *(float4*)(C + (size_t)(row0 + ty*4 + r)*HH + col0 + tx*4) = o;
    }
}

// s_i = Wh[i]·a_src, d_i = Wh[i]·a_dst; also emit sortable u64 key of d.
__global__ void k_sd(const float* __restrict__ Wh, const float* __restrict__ a_src,
                     const float* __restrict__ a_dst, float* ws) {
    int wave = threadIdx.x >> 6, lane = threadIdx.x & 63;
    int row = blockIdx.x*4 + wave;
    float4 wh = *(const float4*)(Wh + (size_t)row*HH + lane*4);
    float4 as = *(const float4*)(a_src + lane*4);
    float4 ad = *(const float4*)(a_dst + lane*4);
    float ss = wh.x*as.x + wh.y*as.y + wh.z*as.z + wh.w*as.w;
    float dd = wh.x*ad.x + wh.y*ad.y + wh.z*ad.z + wh.w*ad.w;
    #pragma unroll
    for (int off = 32; off; off >>= 1) {
        ss += __shfl_xor(ss, off);
        dd += __shfl_xor(dd, off);
    }
    if (lane == 0) {
        ws[OFF_S+row] = ss; ws[OFF_D+row] = dd;
        unsigned u = __float_as_uint(dd);
        unsigned mono = u ^ ((u & 0x80000000u) ? 0xFFFFFFFFu : 0x80000000u);
        ((unsigned long long*)(ws + OFF_KEYS))[row] =
            (((unsigned long long)mono) << 13) | (unsigned)row;
    }
}

// rank by counting with u64 keys: one v_cmp_lt_u64 per compare, branchless,
// tie-break exact (index in low bits). 512 blocks (2/CU); wave ranks 4 j's
// over all 8192 q; contiguous ds_read_b128 (2 keys) -> 2-way alias = free.
__global__ __launch_bounds__(256) void k_rank(float* ws) {
    __shared__ unsigned long long lk[NN];   // 64 KB
    const unsigned long long* keys = (const unsigned long long*)(ws + OFF_KEYS);
    int tid = threadIdx.x;
    for (int m = tid; m < NN/2; m += 256)
        *(ulonglong2*)&lk[m*2] = *(const ulonglong2*)&keys[m*2];
    __syncthreads();
    int wave = tid >> 6, lane = tid & 63;
    int jb = blockIdx.x*16 + wave*4;
    unsigned long long kj0 = lk[jb+0], kj1 = lk[jb+1];
    unsigned long long kj2 = lk[jb+2], kj3 = lk[jb+3];
    int c0 = 0, c1 = 0, c2 = 0, c3 = 0;
    #pragma unroll 4
    for (int it = 0; it < 64; ++it) {
        ulonglong2 kq = *(const ulonglong2*)&lk[(it*64 + lane)*2];
        c0 += (kq.x < kj0); c1 += (kq.x < kj1);
        c2 += (kq.x < kj2); c3 += (kq.x < kj3);
        c0 += (kq.y < kj0); c1 += (kq.y < kj1);
        c2 += (kq.y < kj2); c3 += (kq.y < kj3);
    }
    #pragma unroll
    for (int off = 1; off < 64; off <<= 1) {
        c0 += __shfl_xor(c0, off);
        c1 += __shfl_xor(c1, off);
        c2 += __shfl_xor(c2, off);
        c3 += __shfl_xor(c3, off);
    }
    if (lane == 0) {
        unsigned long long kk[4] = {kj0, kj1, kj2, kj3};
        int cr[4] = {c0, c1, c2, c3};
        #pragma unroll
        for (int q = 0; q < 4; ++q) {
            unsigned long long kv = kk[q];
            int r = cr[q];
            unsigned mm = (unsigned)(kv >> 13);
            unsigned u = (mm & 0x80000000u) ? (mm ^ 0x80000000u) : ~mm;
            float dj = __uint_as_float(u);
            int j = (int)(kv & 8191ULL);
            ws[OFF_SORTD + r] = dj;
            ((int*)ws)[OFF_PERM + r] = j;
            ws[OFF_EA + r] = expf(ALPHAC * dj);
            ws[OFF_E1 + r] = expf(dj);
        }
    }
}

// inclusive scalar prefix sums of ea, e1 over sorted order (1 block)
__global__ void k_scan_scalar(float* ws) {
    __shared__ float sa[256], sb[256];
    int t = threadIdx.x;
    const float* ea = ws + OFF_EA;
    const float* e1 = ws + OFF_E1;
    int base = t * 32;
    float ta = 0.f, tb = 0.f;
    #pragma unroll
    for (int q = 0; q < 8; ++q) {
        float4 va = *(const float4*)&ea[base + q*4];
        float4 vb = *(const float4*)&e1[base + q*4];
        ta += va.x + va.y + va.z + va.w;
        tb += vb.x + vb.y + vb.z + vb.w;
    }
    sa[t] = ta; sb[t] = tb;
    __syncthreads();
    for (int off = 1; off < 256; off <<= 1) {
        float xa = (t >= off) ? sa[t-off] : 0.f;
        float xb = (t >= off) ? sb[t-off] : 0.f;
        __syncthreads();
        sa[t] += xa; sb[t] += xb;
        __syncthreads();
    }
    float ra = sa[t] - ta, rb = sb[t] - tb;
    #pragma unroll
    for (int q = 0; q < 8; ++q) {
        float4 va = *(const float4*)&ea[base + q*4];
        float4 vb = *(const float4*)&e1[base + q*4];
        float4 oa, ob;
        ra += va.x; oa.x = ra;  rb += vb.x; ob.x = rb;
        ra += va.y; oa.y = ra;  rb += vb.y; ob.y = rb;
        ra += va.z; oa.z = ra;  rb += vb.z; ob.z = rb;
        ra += va.w; oa.w = ra;  rb += vb.w; ob.w = rb;
        *(float4*)&ws[OFF_APREF + base + q*4] = oa;
        *(float4*)&ws[OFF_BPREF + base + q*4] = ob;
    }
}

// per-chunk (32) inclusive vector prefixes of exp(alpha d)*Wh and exp(d)*Wh.
// Chunk totals written to CPA/CPB slot c+1 (scanned in place by k_chunkscan).
__global__ __launch_bounds__(256) void k_vecpref(float* ws) {
    __shared__ int   sp[CHUNK];
    __shared__ float sea[CHUNK], se1[CHUNK];
    int c = blockIdx.x, h = threadIdx.x;
    int k0 = c * CHUNK;
    if (h < CHUNK) {
        sp[h]  = ((int*)ws)[OFF_PERM + k0 + h];
        sea[h] = ws[OFF_EA + k0 + h];
        se1[h] = ws[OFF_E1 + k0 + h];
    }
    __syncthreads();
    const float* Wh = ws + OFF_WH;
    float wv[CHUNK];
    #pragma unroll
    for (int kk = 0; kk < CHUNK; ++kk)
        wv[kk] = Wh[(size_t)sp[kk]*HH + h];     // 32 independent loads
    float acca = 0.f, accb = 0.f;
    #pragma unroll
    for (int kk = 0; kk < CHUNK; ++kk) {
        acca += sea[kk]*wv[kk]; accb += se1[kk]*wv[kk];
        ws[OFF_APART + (size_t)(k0+kk)*HH + h] = acca;
        ws[OFF_BPART + (size_t)(k0+kk)*HH + h] = accb;
    }
    ws[OFF_CPA + (size_t)(c+1)*HH + h] = acca;
    ws[OFF_CPB + (size_t)(c+1)*HH + h] = accb;
}

// in-place exclusive scan of chunk totals: CPA[c] <- sum of totals[0..c-1].
// 32 blocks x 256 thr: 8 h-columns/block, 32 lanes/column, 8 chunks/lane.
__global__ __launch_bounds__(256) void k_chunkscan(float* ws) {
    int tid = threadIdx.x;
    int h = blockIdx.x*8 + (tid >> 5);
    int t = tid & 31;
    float la[8], lb[8];
    float ta = 0.f, tb = 0.f;
    #pragma unroll
    for (int m = 0; m < 8; ++m) {
        int c = t*8 + m;
        la[m] = ws[OFF_CPA + (size_t)(c+1)*HH + h];
        lb[m] = ws[OFF_CPB + (size_t)(c+1)*HH + h];
        ta += la[m]; tb += lb[m];
    }
    float ia = ta, ib = tb;
    #pragma unroll
    for (int off = 1; off < 32; off <<= 1) {
        float xa = __shfl_up(ia, off, 32);
        float xb = __shfl_up(ib, off, 32);
        if (t >= off) { ia += xa; ib += xb; }
    }
    float ba = ia - ta, bb = ib - tb;   // exclusive base
    __syncthreads();                    // all reads precede in-place writes
    #pragma unroll
    for (int m = 0; m < 8; ++m) {
        int c = t*8 + m;
        ws[OFF_CPA + (size_t)c*HH + h] = ba; ba += la[m];
        ws[OFF_CPB + (size_t)c*HH + h] = bb; bb += lb[m];
    }
    if (t == 31) {
        ws[OFF_CPA + (size_t)NCHUNK*HH + h] = ba;
        ws[OFF_CPB + (size_t)NCHUNK*HH + h] = bb;
    }
}

__global__ void k_deg(const int* __restrict__ ei, float* ws) {
    int e = blockIdx.x*256 + threadIdx.x;
    if (e < EE) atomicAdd(ws + OFF_DEG + ei[e], 1.0f);
}

__global__ void k_dinv(float* ws) {
    int i = blockIdx.x*256 + threadIdx.x;
    if (i < NN) {
        float dv = rsqrtf(ws[OFF_DEG + i] + 1.0f);   // +1 = self-loop
        ws[OFF_DINV + i] = dv;
        ws[OFF_WNODE + i] = dv*dv;                   // self-loop term
    }
}

__global__ void k_wnode(const int* __restrict__ ei, float* ws) {
    int e = blockIdx.x*256 + threadIdx.x;
    if (e < EE) {
        int r = ei[e], c = ei[EE + e];
        atomicAdd(ws + OFF_WNODE + c, ws[OFF_DINV + r] * ws[OFF_DINV + c]);
    }
}

__device__ __forceinline__ float elu1(float x) {
    return x > 0.f ? x : (expf(x) - 1.f);
}

// per-row attention via prefix lookup; accumulate v = sum_i wnode[i]*h1[i].
// 512 blocks; 4 rows per wave; binary searches parallel on lanes 0..3 (x16).
__global__ __launch_bounds__(256) void k_rows(float* ws) {
    __shared__ float sd[NN];       // 32 KB sorted d
    __shared__ float red[4][256];
    int tid = threadIdx.x;
    for (int m = tid; m < NN/4; m += 256)
        *(float4*)&sd[m*4] = *(const float4*)(ws + OFF_SORTD + m*4);
    __syncthreads();
    int wave = tid >> 6, lane = tid & 63;
    int gw = blockIdx.x*4 + wave;            // 0..2047
    const float* apart = ws + OFF_APART;
    const float* bpart = ws + OFF_BPART;
    const float* cpa = ws + OFF_CPA;
    const float* cpb = ws + OFF_CPB;
    float btot = ws[OFF_BPREF + NN - 1];
    float4 BT = *(const float4*)(cpb + (size_t)NCHUNK*HH + lane*4);

    int myr = lane & 3;
    float si_m = ws[OFF_S + gw*4 + myr];
    float tt = -si_m;
    int lo = 0, hi = NN;
    while (lo < hi) {
        int mid = (lo + hi) >> 1;
        if (sd[mid] <= tt) lo = mid + 1; else hi = mid;
    }

    float accx = 0.f, accy = 0.f, accz = 0.f, accw = 0.f;
    #pragma unroll
    for (int r = 0; r < 4; ++r) {
        int i = gw*4 + r;
        int k = __shfl(lo, r);
        float si = __shfl(si_m, r);
        float eas = expf(ALPHAC * si), es = expf(si);
        float av = 0.f, bv = 0.f;
        float Ax=0.f, Ay=0.f, Az=0.f, Aw=0.f, Bx=0.f, By=0.f, Bz=0.f, Bw=0.f;
        if (k > 0) {
            int km = k - 1, cc = km >> 5;
            av = ws[OFF_APREF + km]; bv = ws[OFF_BPREF + km];
            float4 pa = *(const float4*)(apart + (size_t)km*HH + lane*4);
            float4 ca = *(const float4*)(cpa + (size_t)cc*HH + lane*4);
            float4 pb = *(const float4*)(bpart + (size_t)km*HH + lane*4);
            float4 cb = *(const float4*)(cpb + (size_t)cc*HH + lane*4);
            Ax = pa.x + ca.x; Ay = pa.y + ca.y; Az = pa.z + ca.z; Aw = pa.w + ca.w;
            Bx = pb.x + cb.x; By = pb.y + cb.y; Bz = pb.z + cb.z; Bw = pb.w + cb.w;
        }
        float Z = eas*av + es*(btot - bv);
        float invZ = 1.f / Z;
        float w = ws[OFF_WNODE + i];
        accx += w * elu1((eas*Ax + es*(BT.x - Bx)) * invZ);
        accy += w * elu1((eas*Ay + es*(BT.y - By)) * invZ);
        accz += w * elu1((eas*Az + es*(BT.z - Bz)) * invZ);
        accw += w * elu1((eas*Aw + es*(BT.w - Bw)) * invZ);
    }
    red[wave][lane*4+0] = accx;
    red[wave][lane*4+1] = accy;
    red[wave][lane*4+2] = accz;
    red[wave][lane*4+3] = accw;
    __syncthreads();
    float sum = red[0][tid] + red[1][tid] + red[2][tid] + red[3][tid];
    atomicAdd(ws + OFF_V + tid, sum);
}

// head: (v @ gcn_w)/N + gcn_b -> @ out_w + out_b -> softmax(2)
__global__ void k_final(const float* __restrict__ gcn_w, const float* __restrict__ gcn_b,
                        const float* __restrict__ out_w, const float* __restrict__ out_b,
                        float* ws, float* out) {
    __shared__ float vl[HH];
    __shared__ float r0s[256], r1s[256];
    int t = threadIdx.x;
    vl[t] = ws[OFF_V + t];
    __syncthreads();
    float acc = 0.f;
    for (int h = 0; h < HH; ++h) acc += vl[h] * gcn_w[(size_t)h*HH + t];
    float meanv = acc * (1.0f/(float)NN) + gcn_b[t];
    r0s[t] = meanv * out_w[t*2+0];
    r1s[t] = meanv * out_w[t*2+1];
    __syncthreads();
    for (int off = 128; off; off >>= 1) {
        if (t < off) { r0s[t] += r0s[t+off]; r1s[t] += r1s[t+off]; }
        __syncthreads();
    }
    if (t == 0) {
        float res0 = r0s[0] + out_b[0], res1 = r1s[0] + out_b[1];
        float m = fmaxf(res0, res1);
        float e0 = expf(res0 - m), e1v = expf(res1 - m);
        float inv = 1.f / (e0 + e1v);
        out[0] = e0 * inv;
        out[1] = e1v * inv;
    }
}

extern "C" void kernel_launch(void* const* d_in, const int* in_sizes, int n_in,
                              void* d_out, int out_size, void* d_ws, size_t ws_size,
                              hipStream_t stream) {
    const float* features = (const float*)d_in[0];
    const int*   eidx     = (const int*)d_in[1];
    const float* W_att    = (const float*)d_in[2];
    const float* a_src    = (const float*)d_in[3];
    const float* a_dst    = (const float*)d_in[4];
    const float* gcn_w    = (const float*)d_in[5];
    const float* gcn_b    = (const float*)d_in[6];
    const float* out_w    = (const float*)d_in[7];
    const float* out_b    = (const float*)d_in[8];
    float* ws  = (float*)d_ws;
    float* out = (float*)d_out;

    hipMemsetAsync(ws + OFF_DEG, 0, (NN + HH)*sizeof(float), stream);  // DEG + V
    k_gemm_wh<<<dim3(NN/64, HH/64), 256, 0, stream>>>(features, W_att, ws + OFF_WH);
    k_sd<<<NN/4, 256, 0, stream>>>(ws + OFF_WH, a_src, a_dst, ws);
    k_rank<<<NN/16, 256, 0, stream>>>(ws);
    k_scan_scalar<<<1, 256, 0, stream>>>(ws);
    k_vecpref<<<NCHUNK, 256, 0, stream>>>(ws);
    k_chunkscan<<<HH/8, 256, 0, stream>>>(ws);
    k_deg<<<EE/256, 256, 0, stream>>>(eidx, ws);
    k_dinv<<<NN/256, 256, 0, stream>>>(ws);
    k_wnode<<<EE/256, 256, 0, stream>>>(eidx, ws);
    k_rows<<<NN/16, 256, 0, stream>>>(ws);
    k_final<<<1, 256, 0, stream>>>(gcn_w, gcn_b, out_w, out_b, ws, out);
}

// Round 4
// 163.598 us; speedup vs baseline: 1.5987x; 1.1341x over previous
//
#include <hip/hip_runtime.h>
#include <hip/hip_bf16.h>

#define NN 8192
#define HH 256
#define EE (NN*32)
#define ALPHAC 0.2f
#define CHUNK 16
#define NCHUNK (NN/CHUNK)   // 512
#define CSPAD 1024

typedef __bf16 bf16x8 __attribute__((ext_vector_type(8)));
typedef float  f32x4  __attribute__((ext_vector_type(4)));

// workspace layout (float offsets)
#define OFF_WH     0
#define OFF_S      (OFF_WH + NN*HH)
#define OFF_D      (OFF_S + NN)
#define OFF_SORTD  (OFF_D + NN)
#define OFF_PERM   (OFF_SORTD + NN)            /* ints */
#define OFF_EA     (OFF_PERM + NN)
#define OFF_E1     (OFF_EA + NN)
#define OFF_SAREL  (OFF_E1 + NN)               /* intra-chunk inclusive prefix of EA */
#define OFF_SBREL  (OFF_SAREL + NN)
#define OFF_ABPART (OFF_SBREL + NN)            /* float2 x NN*HH */
#define OFF_CPAB   (OFF_ABPART + 2*NN*HH)      /* float2 x (NCHUNK+1)*HH */
#define OFF_CSA    (OFF_CPAB + 2*(NCHUNK+1)*HH)
#define OFF_CSB    (OFF_CSA + CSPAD)
#define OFF_DEG    (OFF_CSB + CSPAD)
#define OFF_V      (OFF_DEG + NN)              /* adjacent to DEG: one zero range */
#define OFF_DINV   (OFF_V + HH)
#define OFF_WNODE  (OFF_DINV + NN)
#define OFF_KEYS   (OFF_WNODE + NN)            /* u64 x NN */
#define OFF_FB16   (OFF_KEYS + 2*NN)           /* bf16 x NN*HH */
#define OFF_WT16   (OFF_FB16 + NN*HH/2)        /* bf16 x HH*HH (W_att^T) */
// total ~ 7.8M floats ~ 31 MiB

// prep: convert features->bf16, build W_att^T bf16, zero DEG+V
__global__ __launch_bounds__(256) void k_prep(const float* __restrict__ features,
                                              const float* __restrict__ W_att,
                                              float* ws) {
    int bid = blockIdx.x, tid = threadIdx.x;
    if (bid < 1024) {
        int base = (bid*256 + tid)*8;
        float4 a = *(const float4*)(features + base);
        float4 b = *(const float4*)(features + base + 4);
        bf16x8 v;
        v[0]=(__bf16)a.x; v[1]=(__bf16)a.y; v[2]=(__bf16)a.z; v[3]=(__bf16)a.w;
        v[4]=(__bf16)b.x; v[5]=(__bf16)b.y; v[6]=(__bf16)b.z; v[7]=(__bf16)b.w;
        *(bf16x8*)((__bf16*)(ws + OFF_FB16) + base) = v;
    } else if (bid < 1056) {
        int idx0 = ((bid-1024)*256 + tid)*8;
        __bf16* WT = (__bf16*)(ws + OFF_WT16);
        #pragma unroll
        for (int q = 0; q < 8; ++q) {
            int idx = idx0 + q;
            int n = idx >> 8, k = idx & 255;
            WT[idx] = (__bf16)W_att[(size_t)k*HH + n];
        }
    } else {
        int z0 = ((bid-1056)*256 + tid)*8;
        #pragma unroll
        for (int q = 0; q < 8; ++q) {
            int i = z0 + q;
            if (i < NN + HH) ws[OFF_DEG + i] = 0.f;
        }
    }
}

// Wh = features @ W_att via MFMA bf16 (f32 accum, direct frag loads, no LDS)
// + fused k_deg (blocks 512..1535)
__global__ __launch_bounds__(256) void k_gemm_deg(const int* __restrict__ ei, float* ws) {
    int bid = blockIdx.x, tid = threadIdx.x;
    if (bid < 512) {
        int mt = bid >> 2, nt = bid & 3;
        int wave = tid >> 6, lane = tid & 63;
        int ml = lane & 15, quad = lane >> 4;
        int row0 = mt*64 + wave*16;
        int n0 = nt*64;
        const __bf16* FB = (const __bf16*)(ws + OFF_FB16);
        const __bf16* WT = (const __bf16*)(ws + OFF_WT16);
        const __bf16* Ap = FB + (size_t)(row0 + ml)*HH + quad*8;
        const __bf16* B0 = WT + (size_t)(n0 +  0 + ml)*HH + quad*8;
        const __bf16* B1 = WT + (size_t)(n0 + 16 + ml)*HH + quad*8;
        const __bf16* B2 = WT + (size_t)(n0 + 32 + ml)*HH + quad*8;
        const __bf16* B3 = WT + (size_t)(n0 + 48 + ml)*HH + quad*8;
        f32x4 ac0 = {0.f,0.f,0.f,0.f}, ac1 = ac0, ac2 = ac0, ac3 = ac0;
        #pragma unroll
        for (int k0 = 0; k0 < HH; k0 += 32) {
            bf16x8 af = *(const bf16x8*)(Ap + k0);
            ac0 = __builtin_amdgcn_mfma_f32_16x16x32_bf16(af, *(const bf16x8*)(B0 + k0), ac0, 0, 0, 0);
            ac1 = __builtin_amdgcn_mfma_f32_16x16x32_bf16(af, *(const bf16x8*)(B1 + k0), ac1, 0, 0, 0);
            ac2 = __builtin_amdgcn_mfma_f32_16x16x32_bf16(af, *(const bf16x8*)(B2 + k0), ac2, 0, 0, 0);
            ac3 = __builtin_amdgcn_mfma_f32_16x16x32_bf16(af, *(const bf16x8*)(B3 + k0), ac3, 0, 0, 0);
        }
        float* Whp = ws + OFF_WH;
        #pragma unroll
        for (int r = 0; r < 4; ++r) {
            size_t grow = (size_t)(row0 + quad*4 + r)*HH + n0 + ml;
            Whp[grow +  0] = ac0[r];
            Whp[grow + 16] = ac1[r];
            Whp[grow + 32] = ac2[r];
            Whp[grow + 48] = ac3[r];
        }
    } else {
        int e = (bid - 512)*256 + tid;
        atomicAdd(ws + OFF_DEG + ei[e], 1.0f);
    }
}

// s_i, d_i + sortable u64 key (blocks < 2048); dinv/wnode-init (blocks 2048..2079)
__global__ __launch_bounds__(256) void k_sd_dinv(float* ws) {
    int bid = blockIdx.x, tid = threadIdx.x;
    if (bid < 2048) {
        int wave = tid >> 6, lane = tid & 63;
        int row = bid*4 + wave;
        const float* Wh = ws + OFF_WH;
        float4 wh = *(const float4*)(Wh + (size_t)row*HH + lane*4);
        // a_src/a_dst staged at head of ABPART region is unsafe; read from params via ws? kept in constant args below
        // (a_src/a_dst passed separately)
        (void)wh;
    }
    (void)ws;
}

// real k_sd_dinv with vector args
__global__ __launch_bounds__(256) void k_sd_dinv2(const float* __restrict__ a_src,
                                                  const float* __restrict__ a_dst,
                                                  float* ws) {
    int bid = blockIdx.x, tid = threadIdx.x;
    if (bid < 2048) {
        int wave = tid >> 6, lane = tid & 63;
        int row = bid*4 + wave;
        const float* Wh = ws + OFF_WH;
        float4 wh = *(const float4*)(Wh + (size_t)row*HH + lane*4);
        float4 as = *(const float4*)(a_src + lane*4);
        float4 ad = *(const float4*)(a_dst + lane*4);
        float ss = wh.x*as.x + wh.y*as.y + wh.z*as.z + wh.w*as.w;
        float dd = wh.x*ad.x + wh.y*ad.y + wh.z*ad.z + wh.w*ad.w;
        #pragma unroll
        for (int off = 32; off; off >>= 1) {
            ss += __shfl_xor(ss, off);
            dd += __shfl_xor(dd, off);
        }
        if (lane == 0) {
            ws[OFF_S+row] = ss; ws[OFF_D+row] = dd;
            unsigned u = __float_as_uint(dd);
            unsigned mono = u ^ ((u & 0x80000000u) ? 0xFFFFFFFFu : 0x80000000u);
            ((unsigned long long*)(ws + OFF_KEYS))[row] =
                (((unsigned long long)mono) << 13) | (unsigned)row;
        }
    } else {
        int i = (bid - 2048)*256 + tid;
        float dv = rsqrtf(ws[OFF_DEG + i] + 1.0f);   // +1 = self-loop
        ws[OFF_DINV + i] = dv;
        ws[OFF_WNODE + i] = dv*dv;                   // self-loop term
    }
}

// rank by counting with u64 keys (branchless v_cmp_lt_u64)
__global__ __launch_bounds__(256) void k_rank(float* ws) {
    __shared__ unsigned long long lk[NN];   // 64 KB
    const unsigned long long* keys = (const unsigned long long*)(ws + OFF_KEYS);
    int tid = threadIdx.x;
    for (int m = tid; m < NN/2; m += 256)
        *(ulonglong2*)&lk[m*2] = *(const ulonglong2*)&keys[m*2];
    __syncthreads();
    int wave = tid >> 6, lane = tid & 63;
    int jb = blockIdx.x*16 + wave*4;
    unsigned long long kj0 = lk[jb+0], kj1 = lk[jb+1];
    unsigned long long kj2 = lk[jb+2], kj3 = lk[jb+3];
    int c0 = 0, c1 = 0, c2 = 0, c3 = 0;
    #pragma unroll 4
    for (int it = 0; it < 64; ++it) {
        ulonglong2 kq = *(const ulonglong2*)&lk[(it*64 + lane)*2];
        c0 += (kq.x < kj0); c1 += (kq.x < kj1);
        c2 += (kq.x < kj2); c3 += (kq.x < kj3);
        c0 += (kq.y < kj0); c1 += (kq.y < kj1);
        c2 += (kq.y < kj2); c3 += (kq.y < kj3);
    }
    #pragma unroll
    for (int off = 1; off < 64; off <<= 1) {
        c0 += __shfl_xor(c0, off);
        c1 += __shfl_xor(c1, off);
        c2 += __shfl_xor(c2, off);
        c3 += __shfl_xor(c3, off);
    }
    if (lane == 0) {
        unsigned long long kk[4] = {kj0, kj1, kj2, kj3};
        int cr[4] = {c0, c1, c2, c3};
        #pragma unroll
        for (int q = 0; q < 4; ++q) {
            unsigned long long kv = kk[q];
            int r = cr[q];
            unsigned mm = (unsigned)(kv >> 13);
            unsigned u = (mm & 0x80000000u) ? (mm ^ 0x80000000u) : ~mm;
            float dj = __uint_as_float(u);
            int j = (int)(kv & 8191ULL);
            ws[OFF_SORTD + r] = dj;
            ((int*)ws)[OFF_PERM + r] = j;
            ws[OFF_EA + r] = expf(ALPHAC * dj);
            ws[OFF_E1 + r] = expf(dj);
        }
    }
}

// vecpref (blocks < NCHUNK): per-chunk(16) vector prefixes (float2-interleaved)
// + intra-chunk scalar prefixes + chunk totals. wnode (blocks NCHUNK..NCHUNK+1023).
__global__ __launch_bounds__(256) void k_wnode_vecpref(const int* __restrict__ ei, float* ws) {
    int bid = blockIdx.x, tid = threadIdx.x;
    if (bid < NCHUNK) {
        __shared__ int   sp[CHUNK];
        __shared__ float sea[CHUNK], se1[CHUNK];
        int c = bid, h = tid;
        int k0 = c * CHUNK;
        if (h < CHUNK) {
            sp[h]  = ((int*)ws)[OFF_PERM + k0 + h];
            sea[h] = ws[OFF_EA + k0 + h];
            se1[h] = ws[OFF_E1 + k0 + h];
        }
        __syncthreads();
        if (tid < 64) {   // wave 0: scalar intra-chunk scans via shfl
            int lane = tid;
            float v = 0.f;
            if (lane < 16) v = sea[lane];
            else if (lane < 32) v = se1[lane-16];
            #pragma unroll
            for (int off = 1; off < 16; off <<= 1) {
                float x = __shfl_up(v, off);
                if ((lane & 15) >= off) v += x;
            }
            if (lane < 16) {
                ws[OFF_SAREL + k0 + lane] = v;
                if (lane == 15) ws[OFF_CSA + c + 1] = v;
            } else if (lane < 32) {
                ws[OFF_SBREL + k0 + lane - 16] = v;
                if (lane == 31) ws[OFF_CSB + c + 1] = v;
            }
        }
        const float* Wh = ws + OFF_WH;
        float wv[CHUNK];
        #pragma unroll
        for (int kk = 0; kk < CHUNK; ++kk)
            wv[kk] = Wh[(size_t)sp[kk]*HH + h];
        float2* abp = (float2*)(ws + OFF_ABPART);
        float acca = 0.f, accb = 0.f;
        #pragma unroll
        for (int kk = 0; kk < CHUNK; ++kk) {
            acca += sea[kk]*wv[kk]; accb += se1[kk]*wv[kk];
            abp[(size_t)(k0+kk)*HH + h] = make_float2(acca, accb);
        }
        float2* cp = (float2*)(ws + OFF_CPAB);
        cp[(size_t)(c+1)*HH + h] = make_float2(acca, accb);
    } else {
        int e = (bid - NCHUNK)*256 + tid;
        int r = ei[e], cix = ei[EE + e];
        atomicAdd(ws + OFF_WNODE + cix, ws[OFF_DINV + r] * ws[OFF_DINV + cix]);
    }
}

// in-place exclusive scan of chunk totals (blocks 0..31: vector float2; block 32: scalars)
__global__ __launch_bounds__(256) void k_chunkscan(float* ws) {
    int bid = blockIdx.x, tid = threadIdx.x;
    if (bid < 32) {
        int h = bid*8 + (tid >> 5);
        int t = tid & 31;
        float2* cp = (float2*)(ws + OFF_CPAB);
        float la[16], lb[16];
        float ta = 0.f, tb = 0.f;
        #pragma unroll
        for (int m = 0; m < 16; ++m) {
            float2 v = cp[(size_t)(t*16 + m + 1)*HH + h];
            la[m] = v.x; lb[m] = v.y;
            ta += la[m]; tb += lb[m];
        }
        float ia = ta, ib = tb;
        #pragma unroll
        for (int off = 1; off < 32; off <<= 1) {
            float xa = __shfl_up(ia, off, 32);
            float xb = __shfl_up(ib, off, 32);
            if (t >= off) { ia += xa; ib += xb; }
        }
        float ba = ia - ta, bb = ib - tb;
        __syncthreads();
        #pragma unroll
        for (int m = 0; m < 16; ++m) {
            cp[(size_t)(t*16 + m)*HH + h] = make_float2(ba, bb);
            ba += la[m]; bb += lb[m];
        }
        if (t == 31) cp[(size_t)NCHUNK*HH + h] = make_float2(ba, bb);
    } else {
        int lane = tid & 63, wvi = tid >> 6;
        bool act = wvi < 2;
        float* cs = ws + (wvi == 1 ? OFF_CSB : OFF_CSA);
        float la[8];
        float ta = 0.f;
        if (act) {
            #pragma unroll
            for (int m = 0; m < 8; ++m) { la[m] = cs[lane*8 + m + 1]; ta += la[m]; }
        }
        float ia = ta;
        #pragma unroll
        for (int off = 1; off < 64; off <<= 1) {
            float x = __shfl_up(ia, off);
            if (lane >= off) ia += x;
        }
        float ba = ia - ta;
        __syncthreads();
        if (act) {
            #pragma unroll
            for (int m = 0; m < 8; ++m) { cs[lane*8 + m] = ba; ba += la[m]; }
            if (lane == 63) cs[NCHUNK] = ba;
        }
    }
}

__device__ __forceinline__ float elu1(float x) {
    return x > 0.f ? x : (expf(x) - 1.f);
}

// per-row attention via prefix lookup; accumulate v = sum_i wnode[i]*h1[i]
__global__ __launch_bounds__(256) void k_rows(float* ws) {
    __shared__ float sd[NN];       // 32 KB sorted d
    __shared__ float red[4][256];
    int tid = threadIdx.x;
    for (int m = tid; m < NN/4; m += 256)
        *(float4*)&sd[m*4] = *(const float4*)(ws + OFF_SORTD + m*4);
    __syncthreads();
    int wave = tid >> 6, lane = tid & 63;
    int gw = blockIdx.x*4 + wave;            // 0..2047
    const float2* abp  = (const float2*)(ws + OFF_ABPART);
    const float2* cpab = (const float2*)(ws + OFF_CPAB);
    float btot = ws[OFF_CSB + NCHUNK];
    const float4* btr = (const float4*)(cpab + (size_t)NCHUNK*HH);
    float4 bt0 = btr[lane*2], bt1 = btr[lane*2+1];
    float BTx = bt0.y, BTy = bt0.w, BTz = bt1.y, BTw = bt1.w;

    int myr = lane & 3;
    float si_m = ws[OFF_S + gw*4 + myr];
    float tt = -si_m;
    int lo = 0, hi = NN;
    while (lo < hi) {
        int mid = (lo + hi) >> 1;
        if (sd[mid] <= tt) lo = mid + 1; else hi = mid;
    }

    float accx = 0.f, accy = 0.f, accz = 0.f, accw = 0.f;
    #pragma unroll
    for (int r = 0; r < 4; ++r) {
        int i = gw*4 + r;
        int k = __shfl(lo, r);
        float si = __shfl(si_m, r);
        float eas = expf(ALPHAC * si), es = expf(si);
        float av = 0.f, bv = 0.f;
        float Ax=0.f, Ay=0.f, Az=0.f, Aw=0.f, Bx=0.f, By=0.f, Bz=0.f, Bw=0.f;
        if (k > 0) {
            int km = k - 1, cc = km >> 4;
            av = ws[OFF_CSA + cc] + ws[OFF_SAREL + km];
            bv = ws[OFF_CSB + cc] + ws[OFF_SBREL + km];
            const float4* pr = (const float4*)(abp + (size_t)km*HH);
            const float4* cr = (const float4*)(cpab + (size_t)cc*HH);
            float4 p0 = pr[lane*2], p1 = pr[lane*2+1];
            float4 q0 = cr[lane*2], q1 = cr[lane*2+1];
            Ax = p0.x + q0.x; Bx = p0.y + q0.y;
            Ay = p0.z + q0.z; By = p0.w + q0.w;
            Az = p1.x + q1.x; Bz = p1.y + q1.y;
            Aw = p1.z + q1.z; Bw = p1.w + q1.w;
        }
        float Z = eas*av + es*(btot - bv);
        float invZ = 1.f / Z;
        float w = ws[OFF_WNODE + i];
        accx += w * elu1((eas*Ax + es*(BTx - Bx)) * invZ);
        accy += w * elu1((eas*Ay + es*(BTy - By)) * invZ);
        accz += w * elu1((eas*Az + es*(BTz - Bz)) * invZ);
        accw += w * elu1((eas*Aw + es*(BTw - Bw)) * invZ);
    }
    red[wave][lane*4+0] = accx;
    red[wave][lane*4+1] = accy;
    red[wave][lane*4+2] = accz;
    red[wave][lane*4+3] = accw;
    __syncthreads();
    float sum = red[0][tid] + red[1][tid] + red[2][tid] + red[3][tid];
    atomicAdd(ws + OFF_V + tid, sum);
}

// head: (v @ gcn_w)/N + gcn_b -> @ out_w + out_b -> softmax(2)
__global__ void k_final(const float* __restrict__ gcn_w, const float* __restrict__ gcn_b,
                        const float* __restrict__ out_w, const float* __restrict__ out_b,
                        float* ws, float* out) {
    __shared__ float vl[HH];
    __shared__ float r0s[256], r1s[256];
    int t = threadIdx.x;
    vl[t] = ws[OFF_V + t];
    __syncthreads();
    float acc = 0.f;
    for (int h = 0; h < HH; ++h) acc += vl[h] * gcn_w[(size_t)h*HH + t];
    float meanv = acc * (1.0f/(float)NN) + gcn_b[t];
    r0s[t] = meanv * out_w[t*2+0];
    r1s[t] = meanv * out_w[t*2+1];
    __syncthreads();
    for (int off = 128; off; off >>= 1) {
        if (t < off) { r0s[t] += r0s[t+off]; r1s[t] += r1s[t+off]; }
        __syncthreads();
    }
    if (t == 0) {
        float res0 = r0s[0] + out_b[0], res1 = r1s[0] + out_b[1];
        float m = fmaxf(res0, res1);
        float e0 = expf(res0 - m), e1v = expf(res1 - m);
        float inv = 1.f / (e0 + e1v);
        out[0] = e0 * inv;
        out[1] = e1v * inv;
    }
}

extern "C" void kernel_launch(void* const* d_in, const int* in_sizes, int n_in,
                              void* d_out, int out_size, void* d_ws, size_t ws_size,
                              hipStream_t stream) {
    const float* features = (const float*)d_in[0];
    const int*   eidx     = (const int*)d_in[1];
    const float* W_att    = (const float*)d_in[2];
    const float* a_src    = (const float*)d_in[3];
    const float* a_dst    = (const float*)d_in[4];
    const float* gcn_w    = (const float*)d_in[5];
    const float* gcn_b    = (const float*)d_in[6];
    const float* out_w    = (const float*)d_in[7];
    const float* out_b    = (const float*)d_in[8];
    float* ws  = (float*)d_ws;
    float* out = (float*)d_out;

    k_prep<<<1061, 256, 0, stream>>>(features, W_att, ws);
    k_gemm_deg<<<1536, 256, 0, stream>>>(eidx, ws);
    k_sd_dinv2<<<2080, 256, 0, stream>>>(a_src, a_dst, ws);
    k_rank<<<NN/16, 256, 0, stream>>>(ws);
    k_wnode_vecpref<<<NCHUNK + 1024, 256, 0, stream>>>(eidx, ws);
    k_chunkscan<<<33, 256, 0, stream>>>(ws);
    k_rows<<<NN/16, 256, 0, stream>>>(ws);
    k_final<<<1, 256, 0, stream>>>(gcn_w, gcn_b, out_w, out_b, ws, out);
}